// Round 11
// baseline (96.943 us; speedup 1.0000x reference)
//
#include <hip/hip_runtime.h>
#include <hip/hip_fp16.h>
#include <stdint.h>

// ---------------------------------------------------------------------------
// CIN block: 3 layers of out[b,k,d] = relu(sum_ij h[b,i,d] feat[b,j,d] W[k,i,j] + b[k])
// GEMM view: m=(b,d), Out[k,m] = sum_i W[k,i,:] @ (diag(h[:,i]) F)[:,m]
// R10 = R9 topology + T3/T4/T5 schedule:
//  - 3 x 16KB LDS ring (8-i chunks); stage(q+2) issued DURING chunk q;
//    boundary = counted s_waitcnt vmcnt(12) + s_barrier (never drains).
//  - chunk = 2 phases x 4 steps; all 16 W-frag ds_read_b128 issued at chunk
//    top -> compiler emits counted lgkmcnt before each MFMA cluster.
//  - setprio(1) around each 16-MFMA cluster (phase-split -> T5 pays).
//  - wrapped tail staging keeps vmcnt counts uniform (no branches).
// Wave = 64m x 32k (2 mb), grid 512 = 64 mgrp x 8 kg, 256 thr (4 waves).
// ---------------------------------------------------------------------------

typedef _Float16 half8_t __attribute__((ext_vector_type(8)));
typedef float f32x4 __attribute__((ext_vector_type(4)));
typedef float f32x16 __attribute__((ext_vector_type(16)));
typedef uint32_t u32x4 __attribute__((ext_vector_type(4)));

union H8 {
  half8_t h;
  uint32_t u[4];
  u32x4 q;
};

#define AS1 __attribute__((address_space(1)))
#define AS3 __attribute__((address_space(3)))

static __device__ __forceinline__ uint32_t pkmul(uint32_t x, uint32_t y) {
  __half2 a = __builtin_bit_cast(__half2, x);
  __half2 b = __builtin_bit_cast(__half2, y);
  __half2 r = __hmul2(a, b);
  return __builtin_bit_cast(uint32_t, r);
}

static __device__ __forceinline__ uint32_t pack2h(float a, float b) {
  __half2 r = __floats2half2_rn(a, b);
  return __builtin_bit_cast(uint32_t, r);
}

// ---- fused prep -------------------------------------------------------------
// W [k][i][j] f32 -> Wt chunks [i][kt][g*16+kr][8 f16]; thread = (k,i,j-octet)
// blocks [0,128): W0 ; [128,640): W1 ; [640,1152): W2
// blocks [1152,1216): feat -> F16 [m][32 j] f16, hP0 [mb][4 g8][4 iw][32 m]
__global__ void prep_kernel(const float* __restrict__ W0, const float* __restrict__ W1,
                            const float* __restrict__ W2, const float* __restrict__ feat,
                            uint16_t* __restrict__ Wt0, uint16_t* __restrict__ Wt1,
                            uint16_t* __restrict__ Wt2,
                            uint16_t* __restrict__ F16, uint32_t* __restrict__ hP0) {
  int blk = blockIdx.x;
  if (blk < 1152) {
    const float* W; uint16_t* Wt; int FLsh, base;
    if (blk < 128)      { W = W0; Wt = Wt0; FLsh = 5; base = 0; }
    else if (blk < 640) { W = W1; Wt = Wt1; FLsh = 7; base = 128; }
    else                { W = W2; Wt = Wt2; FLsh = 7; base = 640; }
    int idx4 = (blk - base) * 256 + threadIdx.x;
    int jg = idx4 & 3;
    int i = (idx4 >> 2) & ((1 << FLsh) - 1);
    int k = idx4 >> (2 + FLsh);
    const float* src = W + ((size_t)(k << FLsh) + i) * 32 + jg * 8;
    float4 x0 = *(const float4*)(src);
    float4 x1 = *(const float4*)(src + 4);
    u32x4 o;
    o[0] = pack2h(x0.x, x0.y);
    o[1] = pack2h(x0.z, x0.w);
    o[2] = pack2h(x1.x, x1.y);
    o[3] = pack2h(x1.z, x1.w);
    int kr = k & 15, kt = k >> 4;
    *(u32x4*)((uint32_t*)Wt + (((size_t)i * 16 + kt) * 64 + jg * 16 + kr) * 4) = o;
  } else {
    int m = (blk - 1152) * 256 + threadIdx.x;  // 0..16383
    int b = m >> 5, d = m & 31;
    const float* fb = feat + (size_t)b * 1024 + d;
    uint16_t hs[32];
#pragma unroll
    for (int j = 0; j < 32; ++j)
      hs[j] = __half_as_ushort(__float2half(fb[j * 32]));
    // hP0 [mb][g8][iw][32 m]: pair jp -> (hs[2jp], hs[2jp+1])
    int mb = m >> 5, ml = m & 31;
#pragma unroll
    for (int jp = 0; jp < 16; ++jp) {
      uint32_t pr = (uint32_t)hs[2 * jp] | ((uint32_t)hs[2 * jp + 1] << 16);
      hP0[((size_t)(mb * 4 + (jp >> 2)) * 4 + (jp & 3)) * 32 + ml] = pr;
    }
#pragma unroll
    for (int c = 0; c < 4; ++c) {
      u32x4 q;
      q[0] = (uint32_t)hs[c * 8 + 0] | ((uint32_t)hs[c * 8 + 1] << 16);
      q[1] = (uint32_t)hs[c * 8 + 2] | ((uint32_t)hs[c * 8 + 3] << 16);
      q[2] = (uint32_t)hs[c * 8 + 4] | ((uint32_t)hs[c * 8 + 5] << 16);
      q[3] = (uint32_t)hs[c * 8 + 6] | ((uint32_t)hs[c * 8 + 7] << 16);
      *(u32x4*)(F16 + (size_t)m * 32 + c * 8) = q;
    }
  }
}

// ---- fused CIN layer GEMM ---------------------------------------------------
// grid 512: bx = mgrp*8 + kg. Block 256 thr (4 waves); wave w covers
// mb0 = mgrp*8 + w*2 and mb0+1 (64 m) x 32 k (kg), full K. 32x32x16 MFMA.
template <int FL>
__global__ __launch_bounds__(256) void gemm_cin(
    const uint32_t* __restrict__ hP,    // [mb][FL/8 g8][4 iw][32 m] u32 pairs
    const uint16_t* __restrict__ wt,    // [FL][16 kt][64][8] f16 chunks
    const uint16_t* __restrict__ f16m,  // [16384][32] f16
    const float* __restrict__ bias,     // [256]
    uint32_t* __restrict__ houtP,       // [mb][16 g8][4 iw][32 m], or null
    float* __restrict__ outp,           // [512][512] f32
    int obase, int klo) {
  constexpr int NCHK = FL / 8;    // chunks of 8 i-slices (16KB)
  constexpr int NCM = NCHK - 1;   // power-of-2 mask
  __shared__ __align__(16) char smem[49152];  // 3 x 16KB ring
  const int tid = threadIdx.x;
  const int lane = tid & 63, w = tid >> 6;
  const int l31 = lane & 31, l5 = lane >> 5;
  const int kg = blockIdx.x & 7, mgrp = blockIdx.x >> 3;
  const int mb0 = mgrp * 8 + w * 2;

  // --- resident F fragments (issued first -> oldest in vmcnt queue) ---
  const uint16_t* fb0 = f16m + (size_t)(mb0 * 32 + l31) * 32 + l5 * 8;
  H8 ffA0, ffA1, ffB0, ffB1;
  ffA0.q = *(const u32x4*)(fb0);
  ffA1.q = *(const u32x4*)(fb0 + 16);
  ffB0.q = *(const u32x4*)(fb0 + 1024);
  ffB1.q = *(const u32x4*)(fb0 + 1040);

  // --- W staging: chunk = 8 i x 2KB (kt pair of kg); 4 glds/wave/chunk ---
  const char* wsrc = (const char*)wt + kg * 2048 + (size_t)(tid >> 7) * 16384 +
                     (tid & 127) * 16;
  char* sdst = smem + tid * 16;

#define STAGE(QQ, BUFOFF)                                                     \
  { const char* s_ = wsrc + (size_t)((QQ) & NCM) * 131072;                    \
    char* d_ = sdst + (BUFOFF);                                               \
    _Pragma("unroll") for (int c_ = 0; c_ < 4; ++c_)                          \
      __builtin_amdgcn_global_load_lds(                                       \
          (const AS1 uint32_t*)(s_ + c_ * 32768),                             \
          (AS3 uint32_t*)(d_ + c_ * 4096), 16, 0, 0); }

  // --- h pair streams (per chunk: 4 iw dwords per mb, coalesced) ---
  const uint32_t* hbA = hP + (size_t)mb0 * (FL / 8) * 128 + l31;
  const uint32_t* hbB = hbA + (size_t)(FL / 8) * 128;

#define HLD(QQ, DA, DB)                                                       \
  { const uint32_t* pa_ = hbA + ((QQ) & NCM) * 128;                           \
    const uint32_t* pb_ = hbB + ((QQ) & NCM) * 128;                           \
    DA[0] = pa_[0]; DA[1] = pa_[32]; DA[2] = pa_[64]; DA[3] = pa_[96];        \
    DB[0] = pb_[0]; DB[1] = pb_[32]; DB[2] = pb_[64]; DB[3] = pb_[96]; }

  u32x4 hcA, hcB, hnA, hnB;

  // --- prologue: S(0), S(1), H(0); counted wait for S(0) ---
  STAGE(0, 0)
  STAGE(1, 16384)
  HLD(0, hcA, hcB)

  f32x16 accA = {}, accB = {};
  const char* rbase = smem + ((l31 >> 4) << 10) + (l5 << 8) + ((lane & 15) << 4);

  asm volatile("s_waitcnt vmcnt(12)" ::: "memory");  // ff+S(0) retired
  __builtin_amdgcn_s_barrier();

#define MSTEP(W0_, W1_, HA_, HB_, PSEL)                                           \
  { uint32_t eA_ = __builtin_amdgcn_perm((HA_), (HA_), (PSEL));                   \
    uint32_t eB_ = __builtin_amdgcn_perm((HB_), (HB_), (PSEL));                   \
    H8 bA0_, bA1_, bB0_, bB1_;                                                    \
    _Pragma("unroll") for (int c_ = 0; c_ < 4; ++c_) {                            \
      bA0_.u[c_] = pkmul(ffA0.u[c_], eA_);                                        \
      bA1_.u[c_] = pkmul(ffA1.u[c_], eA_);                                        \
      bB0_.u[c_] = pkmul(ffB0.u[c_], eB_);                                        \
      bB1_.u[c_] = pkmul(ffB1.u[c_], eB_);                                        \
    }                                                                             \
    accA = __builtin_amdgcn_mfma_f32_32x32x16_f16((W0_).h, bA0_.h, accA, 0, 0, 0); \
    accA = __builtin_amdgcn_mfma_f32_32x32x16_f16((W1_).h, bA1_.h, accA, 0, 0, 0); \
    accB = __builtin_amdgcn_mfma_f32_32x32x16_f16((W0_).h, bB0_.h, accB, 0, 0, 0); \
    accB = __builtin_amdgcn_mfma_f32_32x32x16_f16((W1_).h, bB1_.h, accB, 0, 0, 0); }

#define CHUNK(QQ, RDOFF, STOFF, HCA_, HCB_, HNA_, HNB_)                           \
  { const char* rb_ = rbase + (RDOFF);                                            \
    H8 w0, w1, w2, w3, w4, w5, w6, w7, w8, w9, wa, wb, wc, wd, we, wf;            \
    w0.q = *(const u32x4*)(rb_ + 0 * 2048);                                       \
    w1.q = *(const u32x4*)(rb_ + 0 * 2048 + 512);                                 \
    w2.q = *(const u32x4*)(rb_ + 1 * 2048);                                       \
    w3.q = *(const u32x4*)(rb_ + 1 * 2048 + 512);                                 \
    w4.q = *(const u32x4*)(rb_ + 2 * 2048);                                       \
    w5.q = *(const u32x4*)(rb_ + 2 * 2048 + 512);                                 \
    w6.q = *(const u32x4*)(rb_ + 3 * 2048);                                       \
    w7.q = *(const u32x4*)(rb_ + 3 * 2048 + 512);                                 \
    HLD((QQ) + 1, HNA_, HNB_)                                                     \
    STAGE((QQ) + 2, STOFF)                                                        \
    w8.q = *(const u32x4*)(rb_ + 4 * 2048);                                       \
    w9.q = *(const u32x4*)(rb_ + 4 * 2048 + 512);                                 \
    wa.q = *(const u32x4*)(rb_ + 5 * 2048);                                       \
    wb.q = *(const u32x4*)(rb_ + 5 * 2048 + 512);                                 \
    wc.q = *(const u32x4*)(rb_ + 6 * 2048);                                       \
    wd.q = *(const u32x4*)(rb_ + 6 * 2048 + 512);                                 \
    we.q = *(const u32x4*)(rb_ + 7 * 2048);                                       \
    wf.q = *(const u32x4*)(rb_ + 7 * 2048 + 512);                                 \
    __builtin_amdgcn_s_setprio(1);                                                \
    MSTEP(w0, w1, HCA_[0], HCB_[0], 0x01000100u)                                  \
    MSTEP(w2, w3, HCA_[0], HCB_[0], 0x03020302u)                                  \
    MSTEP(w4, w5, HCA_[1], HCB_[1], 0x01000100u)                                  \
    MSTEP(w6, w7, HCA_[1], HCB_[1], 0x03020302u)                                  \
    __builtin_amdgcn_s_setprio(0);                                                \
    __builtin_amdgcn_s_setprio(1);                                                \
    MSTEP(w8, w9, HCA_[2], HCB_[2], 0x01000100u)                                  \
    MSTEP(wa, wb, HCA_[2], HCB_[2], 0x03020302u)                                  \
    MSTEP(wc, wd, HCA_[3], HCB_[3], 0x01000100u)                                  \
    MSTEP(we, wf, HCA_[3], HCB_[3], 0x03020302u)                                  \
    __builtin_amdgcn_s_setprio(0);                                                \
    asm volatile("s_waitcnt vmcnt(12)" ::: "memory");                             \
    __builtin_amdgcn_s_barrier();                                                 \
  }

  int r0 = 0, r1 = 16384, r2 = 32768;
#pragma unroll 1
  for (int q = 0; q < NCHK; q += 2) {
    CHUNK(q, r0, r2, hcA, hcB, hnA, hnB)
    CHUNK(q + 1, r1, r0, hnA, hnB, hcA, hcB)
    int t = r2; r2 = r1; r1 = r0; r0 = t;
  }
#undef CHUNK
#undef MSTEP
#undef STAGE
#undef HLD

  asm volatile("s_waitcnt vmcnt(0)" ::: "memory");  // drain wrapped tail stages

  // ---- epilogue: bias+relu; C row k = 8a + 4*l5 + t, col m = l31 ------------
  f32x4 bv[4];
#pragma unroll
  for (int a = 0; a < 4; ++a)
    bv[a] = *(const f32x4*)(bias + kg * 32 + a * 8 + l5 * 4);

#define EPILOG(ACC, MB)                                                           \
  {                                                                               \
    float v[16];                                                                  \
    _Pragma("unroll") for (int a = 0; a < 4; ++a)                                 \
        _Pragma("unroll") for (int t = 0; t < 4; ++t) {                           \
      float x = ACC[a * 4 + t] + bv[a][t];                                        \
      v[a * 4 + t] = x > 0.f ? x : 0.f;                                           \
    }                                                                             \
    if (houtP != nullptr && kg < 4) {                                             \
      _Pragma("unroll") for (int a = 0; a < 4; ++a)                               \
          _Pragma("unroll") for (int c = 0; c < 2; ++c) {                         \
        uint32_t pr = pack2h(v[a * 4 + 2 * c], v[a * 4 + 2 * c + 1]);             \
        houtP[((size_t)((MB) * 16 + kg * 4 + a) * 4 + 2 * l5 + c) * 32 + l31] =   \
            pr;                                                                   \
      }                                                                           \
    }                                                                             \
    _Pragma("unroll") for (int r = 0; r < 16; ++r) {                              \
      float x = v[r];                                                             \
      x += __shfl_xor(x, 1); x += __shfl_xor(x, 2);                               \
      x += __shfl_xor(x, 4); x += __shfl_xor(x, 8);                               \
      x += __shfl_xor(x, 16);                                                     \
      v[r] = x;                                                                   \
    }                                                                             \
    if (kg * 32 >= klo && (lane == 0 || lane == 32)) {                            \
      float* ob = outp + (size_t)(MB) * 512 + obase + kg * 32 - klo + l5 * 4;     \
      _Pragma("unroll") for (int a = 0; a < 4; ++a)                               \
          *(f32x4*)(ob + a * 8) =                                                 \
              (f32x4){v[a * 4], v[a * 4 + 1], v[a * 4 + 2], v[a * 4 + 3]};        \
    }                                                                             \
  }

  EPILOG(accA, mb0)
  EPILOG(accB, mb0 + 1)
#undef EPILOG
}

// ---------------------------------------------------------------------------
extern "C" void kernel_launch(void* const* d_in, const int* in_sizes, int n_in,
                              void* d_out, int out_size, void* d_ws, size_t ws_size,
                              hipStream_t stream) {
  const float* feat = (const float*)d_in[0];
  const float* W0 = (const float*)d_in[1];
  const float* b0 = (const float*)d_in[2];
  const float* W1 = (const float*)d_in[3];
  const float* b1 = (const float*)d_in[4];
  const float* W2 = (const float*)d_in[5];
  const float* b2 = (const float*)d_in[6];
  float* out = (float*)d_out;
  char* ws = (char*)d_ws;

  // workspace layout (bytes)
  uint16_t* Wt0 = (uint16_t*)(ws + 0x000000);  // 512KB
  uint16_t* Wt1 = (uint16_t*)(ws + 0x080000);  // 2MB
  uint16_t* Wt2 = (uint16_t*)(ws + 0x280000);  // 2MB
  uint16_t* F16 = (uint16_t*)(ws + 0x480000);  // 1MB
  uint32_t* hP0 = (uint32_t*)(ws + 0x580000);  // [512][4][4][32]  u32 = 1MB
  uint32_t* hP1 = (uint32_t*)(ws + 0x680000);  // [512][16][4][32] u32 = 4MB
  uint32_t* hP2 = (uint32_t*)(ws + 0xA80000);  // 4MB (end 14.5MB)

  prep_kernel<<<1216, 256, 0, stream>>>(W0, W1, W2, feat, Wt0, Wt1, Wt2, F16, hP0);

  // layers: out cols [0,128)=L0 k>=128, [128,256)=L1 k>=128, [256,512)=L2 all k
  gemm_cin<32><<<512, 256, 0, stream>>>(hP0, Wt0, F16, b0, hP1, out, 0, 128);
  gemm_cin<128><<<512, 256, 0, stream>>>(hP1, Wt1, F16, b1, hP2, out, 128, 128);
  gemm_cin<128><<<512, 256, 0, stream>>>(hP2, Wt2, F16, b2, (uint32_t*)nullptr,
                                         out, 256, 0);
}